// Round 2
// baseline (682.583 us; speedup 1.0000x reference)
//
#include <hip/hip_runtime.h>

#define DIM 128

using f16 = _Float16;
using f16x4 = __attribute__((ext_vector_type(4))) f16;
using f32x4 = __attribute__((ext_vector_type(4))) float;

// ---------------- CSR build ----------------

// deg[v] = number of directed edges with destination v
__global__ void k_count(const int* __restrict__ u_idx, const int* __restrict__ i_idx,
                        int E, int n_u, int* __restrict__ deg) {
    int i = blockIdx.x * blockDim.x + threadIdx.x;
    int stride = gridDim.x * blockDim.x;
    int total = 2 * E;
    for (; i < total; i += stride) {
        if (i < E) atomicAdd(&deg[u_idx[i]], 1);
        else       atomicAdd(&deg[n_u + i_idx[i - E]], 1);
    }
}

// exclusive scan over deg (3 kernels, n up to 512*1024)
// scan1 also emits rnorm (free fusion: same pass over deg)
__global__ void k_scan1(const int* __restrict__ deg, int n, int* __restrict__ partials,
                        float* __restrict__ rnorm) {
    __shared__ int sh[256];
    int tid = threadIdx.x;
    int base = blockIdx.x * 1024 + tid * 4;
    int s = 0;
#pragma unroll
    for (int j = 0; j < 4; ++j) {
        int idx = base + j;
        if (idx < n) {
            int d = deg[idx];
            s += d;
            // reference deg = 2*d (bincount over [r,c]); rows with d==0 never feed edges
            rnorm[idx] = (d > 0) ? rsqrtf(2.0f * (float)d) : 0.0f;
        }
    }
    sh[tid] = s;
    __syncthreads();
    for (int off = 128; off > 0; off >>= 1) {
        if (tid < off) sh[tid] += sh[tid + off];
        __syncthreads();
    }
    if (tid == 0) partials[blockIdx.x] = sh[0];
}

__global__ void k_scan2(const int* __restrict__ partials, int* __restrict__ offsets, int NB) {
    __shared__ int sh[512];
    int tid = threadIdx.x;
    int v = (tid < NB) ? partials[tid] : 0;
    sh[tid] = v;
    __syncthreads();
    for (int off = 1; off < 512; off <<= 1) {
        int t = (tid >= off) ? sh[tid - off] : 0;
        __syncthreads();
        sh[tid] += t;
        __syncthreads();
    }
    if (tid < NB) offsets[tid] = sh[tid] - v;  // exclusive
}

__global__ void k_scan3(const int* __restrict__ deg, int n,
                        const int* __restrict__ offsets, int* __restrict__ row_ptr, int twoE) {
    __shared__ int sh[256];
    int tid = threadIdx.x;
    int base = blockIdx.x * 1024 + tid * 4;
    int v[4];
    int ts = 0;
#pragma unroll
    for (int j = 0; j < 4; ++j) {
        int idx = base + j;
        v[j] = (idx < n) ? deg[idx] : 0;
        ts += v[j];
    }
    sh[tid] = ts;
    __syncthreads();
    for (int off = 1; off < 256; off <<= 1) {
        int t = (tid >= off) ? sh[tid - off] : 0;
        __syncthreads();
        sh[tid] += t;
        __syncthreads();
    }
    int run = sh[tid] - ts + offsets[blockIdx.x];
#pragma unroll
    for (int j = 0; j < 4; ++j) {
        int idx = base + j;
        if (idx < n) row_ptr[idx] = run;
        run += v[j];
    }
    if (blockIdx.x == 0 && tid == 0) row_ptr[n] = twoE;
}

// merged: adjacency fill (blocks [0,FB)) + fp16 pre-scaled gather source build
// (blocks [FB,grid)): xh0[v] = fp16(rnorm[v] * x0[v]).
// fill is atomic/latency-bound, scale is BW-bound -> good co-scheduling.
__global__ void k_fill_scale(const int* __restrict__ u_idx, const int* __restrict__ i_idx,
                             int E, int n_u, int n,
                             const int* __restrict__ row_ptr,
                             int* __restrict__ cursor, int* __restrict__ adj,
                             const float* __restrict__ u_emb, const float* __restrict__ i_emb,
                             const float* __restrict__ rnorm, f16* __restrict__ xh,
                             int FB) {
    if ((int)blockIdx.x < FB) {
        int i = blockIdx.x * blockDim.x + threadIdx.x;
        int stride = FB * blockDim.x;
        int total = 2 * E;
        for (; i < total; i += stride) {
            int r, c;
            if (i < E) { r = u_idx[i];            c = n_u + i_idx[i]; }
            else       { int t = i - E; r = n_u + i_idx[t]; c = u_idx[t]; }
            int pos = atomicAdd(&cursor[r], 1);
            __builtin_nontemporal_store(c, &adj[row_ptr[r] + pos]);
        }
    } else {
        int g = (blockIdx.x - FB) * blockDim.x + threadIdx.x;
        int stride = (gridDim.x - FB) * blockDim.x;
        int total = n * 32;
        for (; g < total; g += stride) {
            int v = g >> 5;
            int lane = g & 31;
            const float* src = (v < n_u) ? (u_emb + (size_t)v * DIM)
                                         : (i_emb + (size_t)(v - n_u) * DIM);
            float r = rnorm[v];
            f32x4 x = __builtin_nontemporal_load(
                reinterpret_cast<const f32x4*>(src + lane * 4));
            f16x4 o;
            o[0] = (f16)(x[0] * r);
            o[1] = (f16)(x[1] * r);
            o[2] = (f16)(x[2] * r);
            o[3] = (f16)(x[3] * r);
            __builtin_nontemporal_store(
                o, reinterpret_cast<f16x4*>(xh + (size_t)v * DIM + lane * 4));
        }
    }
}

// ---------------- SpMM ----------------
// One 32-lane half-wave per row; 4 fp16 elements (8B) per lane (128 = 32*4).
// Gather source xh is ALWAYS pre-scaled by rnorm[c] (weights folded) -> no
// per-edge weight gather in either layer.
// MODE 0: writes yh[row] = fp16(rnorm[row]^2 * sum) = fp16(rnorm[row]*x1[row])
//         (the pre-scaled gather operand for layer 2)
// MODE 1: writes y[row] = (x0 + x1 + rnorm[row]*sum)/3, recovering
//         x1[row] = yh1[row]/rnorm[row] (deg-0 rows: x1 = 0, guarded).
// Tail is predicated with clamped indices so 4 gathers stay in flight
// (clamped duplicates hit the just-fetched L1 line — free).
// Streaming accesses (adj, x0, output) are nontemporal to keep L2 for the
// gather table.

template <int MODE>
__global__ __launch_bounds__(256) void k_spmm(const int* __restrict__ row_ptr,
                                              const int* __restrict__ adj,
                                              const float* __restrict__ rnorm,
                                              const f16* __restrict__ xh,
                                              const float* __restrict__ u_emb,
                                              const float* __restrict__ i_emb,
                                              int n_u, int n,
                                              float* __restrict__ y,
                                              f16* __restrict__ yh) {
    int g = blockIdx.x * blockDim.x + threadIdx.x;
    int row = g >> 5;
    int lane = g & 31;
    if (row >= n) return;
    int s = row_ptr[row];
    int e = row_ptr[row + 1];
    float rnr = rnorm[row];
    f32x4 acc = {0.f, 0.f, 0.f, 0.f};
    const f16* xb = xh + lane * 4;
    int e1 = e - 1;
    for (int k = s; k < e; k += 4) {
        int k1 = k + 1, k2 = k + 2, k3 = k + 3;
        int c0 = __builtin_nontemporal_load(&adj[k]);
        int c1 = __builtin_nontemporal_load(&adj[(k1 <= e1) ? k1 : e1]);
        int c2 = __builtin_nontemporal_load(&adj[(k2 <= e1) ? k2 : e1]);
        int c3 = __builtin_nontemporal_load(&adj[(k3 <= e1) ? k3 : e1]);
        float w1 = (k1 < e) ? 1.f : 0.f;
        float w2 = (k2 < e) ? 1.f : 0.f;
        float w3 = (k3 < e) ? 1.f : 0.f;
        f16x4 v0 = *reinterpret_cast<const f16x4*>(xb + (size_t)c0 * DIM);
        f16x4 v1 = *reinterpret_cast<const f16x4*>(xb + (size_t)c1 * DIM);
        f16x4 v2 = *reinterpret_cast<const f16x4*>(xb + (size_t)c2 * DIM);
        f16x4 v3 = *reinterpret_cast<const f16x4*>(xb + (size_t)c3 * DIM);
        acc[0] += (float)v0[0];
        acc[1] += (float)v0[1];
        acc[2] += (float)v0[2];
        acc[3] += (float)v0[3];
        acc[0] = fmaf((float)v1[0], w1, acc[0]);
        acc[1] = fmaf((float)v1[1], w1, acc[1]);
        acc[2] = fmaf((float)v1[2], w1, acc[2]);
        acc[3] = fmaf((float)v1[3], w1, acc[3]);
        acc[0] = fmaf((float)v2[0], w2, acc[0]);
        acc[1] = fmaf((float)v2[1], w2, acc[1]);
        acc[2] = fmaf((float)v2[2], w2, acc[2]);
        acc[3] = fmaf((float)v2[3], w2, acc[3]);
        acc[0] = fmaf((float)v3[0], w3, acc[0]);
        acc[1] = fmaf((float)v3[1], w3, acc[1]);
        acc[2] = fmaf((float)v3[2], w3, acc[2]);
        acc[3] = fmaf((float)v3[3], w3, acc[3]);
    }
    if (MODE == 0) {
        float sc = rnr * rnr;  // store rnorm[row] * x1[row]
        f16x4 h;
        h[0] = (f16)(acc[0] * sc);
        h[1] = (f16)(acc[1] * sc);
        h[2] = (f16)(acc[2] * sc);
        h[3] = (f16)(acc[3] * sc);
        __builtin_nontemporal_store(
            h, reinterpret_cast<f16x4*>(yh + (size_t)row * DIM + lane * 4));
    } else {
        const float* x0b = (row < n_u) ? (u_emb + (size_t)row * DIM)
                                       : (i_emb + (size_t)(row - n_u) * DIM);
        f32x4 x0 = __builtin_nontemporal_load(
            reinterpret_cast<const f32x4*>(x0b + lane * 4));
        f16x4 a1 = *reinterpret_cast<const f16x4*>(xh + (size_t)row * DIM + lane * 4);
        float inv = (rnr > 0.f) ? (1.0f / rnr) : 0.f;  // x1 = a1/rnorm
        const float third = 1.0f / 3.0f;
        f32x4 o;
        o[0] = (x0[0] + (float)a1[0] * inv + acc[0] * rnr) * third;
        o[1] = (x0[1] + (float)a1[1] * inv + acc[1] * rnr) * third;
        o[2] = (x0[2] + (float)a1[2] * inv + acc[2] * rnr) * third;
        o[3] = (x0[3] + (float)a1[3] * inv + acc[3] * rnr) * third;
        __builtin_nontemporal_store(
            o, reinterpret_cast<f32x4*>(y + (size_t)row * DIM + lane * 4));
    }
}

// ---------------- host ----------------

static inline int grid_for(long long work, int block, int cap = 4096) {
    long long b = (work + block - 1) / block;
    if (b > cap) b = cap;
    if (b < 1) b = 1;
    return (int)b;
}

extern "C" void kernel_launch(void* const* d_in, const int* in_sizes, int n_in,
                              void* d_out, int out_size, void* d_ws, size_t ws_size,
                              hipStream_t stream) {
    const float* u_emb = (const float*)d_in[0];
    const float* i_emb = (const float*)d_in[1];
    const int* u_idx = (const int*)d_in[2];
    const int* i_idx = (const int*)d_in[3];

    const int n_u = in_sizes[0] / DIM;
    const int n_i = in_sizes[1] / DIM;
    const int n = n_u + n_i;
    const int E = in_sizes[2];
    const int twoE = 2 * E;
    const int NB = (n + 1023) / 1024;  // scan blocks (<= 512)

    // workspace layout
    char* w = (char*)d_ws;
    auto alloc = [&](size_t bytes) -> void* {
        void* p = (void*)w;
        w += (bytes + 255) & ~(size_t)255;
        return p;
    };
    f16*   xh0     = (f16*)alloc((size_t)n * DIM * sizeof(f16));  // rnorm-scaled x0, fp16
    f16*   xh1     = (f16*)alloc((size_t)n * DIM * sizeof(f16));  // rnorm-scaled x1, fp16
    float* rnorm   = (float*)alloc((size_t)n * sizeof(float));
    int*   degcur  = (int*)alloc((size_t)(2 * n) * sizeof(int));  // deg | cursor (one memset)
    int*   deg     = degcur;
    int*   cursor  = degcur + n;
    int*   row_ptr = (int*)alloc((size_t)(n + 1) * sizeof(int));
    int*   adj     = (int*)alloc((size_t)twoE * sizeof(int));
    int*   parts   = (int*)alloc((size_t)NB * sizeof(int));
    int*   offs    = (int*)alloc((size_t)NB * sizeof(int));
    (void)ws_size;

    hipMemsetAsync(degcur, 0, (size_t)(2 * n) * sizeof(int), stream);

    k_count<<<grid_for(twoE, 256, 2048), 256, 0, stream>>>(u_idx, i_idx, E, n_u, deg);
    k_scan1<<<NB, 256, 0, stream>>>(deg, n, parts, rnorm);
    k_scan2<<<1, 512, 0, stream>>>(parts, offs, NB);
    k_scan3<<<NB, 256, 0, stream>>>(deg, n, offs, row_ptr, twoE);

    const int FB = 2048;   // fill blocks (edge work, atomic-bound)
    const int SB = 4096;   // scale blocks (row work, BW-bound)
    k_fill_scale<<<FB + SB, 256, 0, stream>>>(u_idx, i_idx, E, n_u, n, row_ptr,
                                              cursor, adj, u_emb, i_emb, rnorm, xh0, FB);

    int sblocks = (int)(((long long)n * 32 + 255) / 256);
    // layer 1: xh1 = fp16( rnorm^2 * (A_unw @ xh0) ) = rnorm .* x1   (fp16)
    k_spmm<0><<<sblocks, 256, 0, stream>>>(row_ptr, adj, rnorm, xh0, nullptr, nullptr,
                                           n_u, n, nullptr, xh1);
    // layer 2 + fused combine: out = (x0 + xh1/rnorm + rnorm*(A_unw @ xh1))/3
    k_spmm<1><<<sblocks, 256, 0, stream>>>(row_ptr, adj, rnorm, xh1, u_emb, i_emb,
                                           n_u, n, (float*)d_out, nullptr);
}

// Round 3
// 612.655 us; speedup vs baseline: 1.1141x; 1.1141x over previous
//
#include <hip/hip_runtime.h>

#define DIM 128

using f16 = _Float16;
using f16x4 = __attribute__((ext_vector_type(4))) f16;
using f32x4 = __attribute__((ext_vector_type(4))) float;

// ---------------- CSR build ----------------

// deg[v] = number of directed edges with destination v
__global__ void k_count(const int* __restrict__ u_idx, const int* __restrict__ i_idx,
                        int E, int n_u, int* __restrict__ deg) {
    int i = blockIdx.x * blockDim.x + threadIdx.x;
    int stride = gridDim.x * blockDim.x;
    int total = 2 * E;
    for (; i < total; i += stride) {
        if (i < E) atomicAdd(&deg[u_idx[i]], 1);
        else       atomicAdd(&deg[n_u + i_idx[i - E]], 1);
    }
}

// exclusive scan over deg (3 kernels, n up to 512*1024)
// scan1 also emits rnorm (free fusion: same pass over deg)
__global__ void k_scan1(const int* __restrict__ deg, int n, int* __restrict__ partials,
                        float* __restrict__ rnorm) {
    __shared__ int sh[256];
    int tid = threadIdx.x;
    int base = blockIdx.x * 1024 + tid * 4;
    int s = 0;
#pragma unroll
    for (int j = 0; j < 4; ++j) {
        int idx = base + j;
        if (idx < n) {
            int d = deg[idx];
            s += d;
            // reference deg = 2*d (bincount over [r,c]); rows with d==0 never feed edges
            rnorm[idx] = (d > 0) ? rsqrtf(2.0f * (float)d) : 0.0f;
        }
    }
    sh[tid] = s;
    __syncthreads();
    for (int off = 128; off > 0; off >>= 1) {
        if (tid < off) sh[tid] += sh[tid + off];
        __syncthreads();
    }
    if (tid == 0) partials[blockIdx.x] = sh[0];
}

__global__ void k_scan2(const int* __restrict__ partials, int* __restrict__ offsets, int NB) {
    __shared__ int sh[512];
    int tid = threadIdx.x;
    int v = (tid < NB) ? partials[tid] : 0;
    sh[tid] = v;
    __syncthreads();
    for (int off = 1; off < 512; off <<= 1) {
        int t = (tid >= off) ? sh[tid - off] : 0;
        __syncthreads();
        sh[tid] += t;
        __syncthreads();
    }
    if (tid < NB) offsets[tid] = sh[tid] - v;  // exclusive
}

__global__ void k_scan3(const int* __restrict__ deg, int n,
                        const int* __restrict__ offsets, int* __restrict__ row_ptr, int twoE) {
    __shared__ int sh[256];
    int tid = threadIdx.x;
    int base = blockIdx.x * 1024 + tid * 4;
    int v[4];
    int ts = 0;
#pragma unroll
    for (int j = 0; j < 4; ++j) {
        int idx = base + j;
        v[j] = (idx < n) ? deg[idx] : 0;
        ts += v[j];
    }
    sh[tid] = ts;
    __syncthreads();
    for (int off = 1; off < 256; off <<= 1) {
        int t = (tid >= off) ? sh[tid - off] : 0;
        __syncthreads();
        sh[tid] += t;
        __syncthreads();
    }
    int run = sh[tid] - ts + offsets[blockIdx.x];
#pragma unroll
    for (int j = 0; j < 4; ++j) {
        int idx = base + j;
        if (idx < n) row_ptr[idx] = run;
        run += v[j];
    }
    if (blockIdx.x == 0 && tid == 0) row_ptr[n] = twoE;
}

// adjacency fill — scattered 4B stores MUST be normal (L2 write-combining);
// NT here caused 16x partial-line write amplification (round-2 post-mortem).
__global__ void k_fill(const int* __restrict__ u_idx, const int* __restrict__ i_idx,
                       int E, int n_u, const int* __restrict__ row_ptr,
                       int* __restrict__ cursor, int* __restrict__ adj) {
    int i = blockIdx.x * blockDim.x + threadIdx.x;
    int stride = gridDim.x * blockDim.x;
    int total = 2 * E;
    for (; i < total; i += stride) {
        int r, c;
        if (i < E) { r = u_idx[i];            c = n_u + i_idx[i]; }
        else       { int t = i - E; r = n_u + i_idx[t]; c = u_idx[t]; }
        int pos = atomicAdd(&cursor[r], 1);
        adj[row_ptr[r] + pos] = c;
    }
}

// fp16 pre-scaled gather source: xh[v] = fp16(rnorm[v] * x0[v]).
// NT load of emb (streamed; re-read only much later in MODE-1),
// NORMAL store of xh (it is the gather table — must stay cache-resident).
__global__ void k_scale_h(const float* __restrict__ u_emb, const float* __restrict__ i_emb,
                          const float* __restrict__ rnorm, int n_u, int n,
                          f16* __restrict__ xh) {
    int g = blockIdx.x * blockDim.x + threadIdx.x;
    int stride = gridDim.x * blockDim.x;
    int total = n * 32;
    for (; g < total; g += stride) {
        int v = g >> 5;
        int lane = g & 31;
        const float* src = (v < n_u) ? (u_emb + (size_t)v * DIM)
                                     : (i_emb + (size_t)(v - n_u) * DIM);
        float r = rnorm[v];
        f32x4 x = __builtin_nontemporal_load(
            reinterpret_cast<const f32x4*>(src + lane * 4));
        f16x4 o;
        o[0] = (f16)(x[0] * r);
        o[1] = (f16)(x[1] * r);
        o[2] = (f16)(x[2] * r);
        o[3] = (f16)(x[3] * r);
        *reinterpret_cast<f16x4*>(xh + (size_t)v * DIM + lane * 4) = o;
    }
}

// ---------------- SpMM ----------------
// One 32-lane half-wave per row; 4 fp16 elements (8B) per lane (128 = 32*4).
// Gather source xh is ALWAYS pre-scaled by rnorm[c] (weights folded) -> no
// per-edge weight gather in either layer.
// MODE 0: writes yh[row] = fp16(rnorm[row]^2 * sum) = fp16(rnorm[row]*x1[row])
//         (the pre-scaled gather operand for layer 2) — NORMAL store (table).
// MODE 1: writes y[row] = (x0 + x1 + rnorm[row]*sum)/3, recovering
//         x1[row] = yh1[row]/rnorm[row] (deg-0 rows: x1 = 0, guarded).
//         x0 load + y store are NT (pure streams, keep L3 for the table).
// Tail is predicated with clamped indices so 4 gathers stay in flight
// (clamped duplicates hit the just-fetched L1 line — free).

template <int MODE>
__global__ __launch_bounds__(256) void k_spmm(const int* __restrict__ row_ptr,
                                              const int* __restrict__ adj,
                                              const float* __restrict__ rnorm,
                                              const f16* __restrict__ xh,
                                              const float* __restrict__ u_emb,
                                              const float* __restrict__ i_emb,
                                              int n_u, int n,
                                              float* __restrict__ y,
                                              f16* __restrict__ yh) {
    int g = blockIdx.x * blockDim.x + threadIdx.x;
    int row = g >> 5;
    int lane = g & 31;
    if (row >= n) return;
    int s = row_ptr[row];
    int e = row_ptr[row + 1];
    float rnr = rnorm[row];
    f32x4 acc = {0.f, 0.f, 0.f, 0.f};
    const f16* xb = xh + lane * 4;
    int e1 = e - 1;
    for (int k = s; k < e; k += 4) {
        int k1 = k + 1, k2 = k + 2, k3 = k + 3;
        int c0 = adj[k];
        int c1 = adj[(k1 <= e1) ? k1 : e1];
        int c2 = adj[(k2 <= e1) ? k2 : e1];
        int c3 = adj[(k3 <= e1) ? k3 : e1];
        float w1 = (k1 < e) ? 1.f : 0.f;
        float w2 = (k2 < e) ? 1.f : 0.f;
        float w3 = (k3 < e) ? 1.f : 0.f;
        f16x4 v0 = *reinterpret_cast<const f16x4*>(xb + (size_t)c0 * DIM);
        f16x4 v1 = *reinterpret_cast<const f16x4*>(xb + (size_t)c1 * DIM);
        f16x4 v2 = *reinterpret_cast<const f16x4*>(xb + (size_t)c2 * DIM);
        f16x4 v3 = *reinterpret_cast<const f16x4*>(xb + (size_t)c3 * DIM);
        acc[0] += (float)v0[0];
        acc[1] += (float)v0[1];
        acc[2] += (float)v0[2];
        acc[3] += (float)v0[3];
        acc[0] = fmaf((float)v1[0], w1, acc[0]);
        acc[1] = fmaf((float)v1[1], w1, acc[1]);
        acc[2] = fmaf((float)v1[2], w1, acc[2]);
        acc[3] = fmaf((float)v1[3], w1, acc[3]);
        acc[0] = fmaf((float)v2[0], w2, acc[0]);
        acc[1] = fmaf((float)v2[1], w2, acc[1]);
        acc[2] = fmaf((float)v2[2], w2, acc[2]);
        acc[3] = fmaf((float)v2[3], w2, acc[3]);
        acc[0] = fmaf((float)v3[0], w3, acc[0]);
        acc[1] = fmaf((float)v3[1], w3, acc[1]);
        acc[2] = fmaf((float)v3[2], w3, acc[2]);
        acc[3] = fmaf((float)v3[3], w3, acc[3]);
    }
    if (MODE == 0) {
        float sc = rnr * rnr;  // store rnorm[row] * x1[row]
        f16x4 h;
        h[0] = (f16)(acc[0] * sc);
        h[1] = (f16)(acc[1] * sc);
        h[2] = (f16)(acc[2] * sc);
        h[3] = (f16)(acc[3] * sc);
        *reinterpret_cast<f16x4*>(yh + (size_t)row * DIM + lane * 4) = h;
    } else {
        const float* x0b = (row < n_u) ? (u_emb + (size_t)row * DIM)
                                       : (i_emb + (size_t)(row - n_u) * DIM);
        f32x4 x0 = __builtin_nontemporal_load(
            reinterpret_cast<const f32x4*>(x0b + lane * 4));
        f16x4 a1 = *reinterpret_cast<const f16x4*>(xh + (size_t)row * DIM + lane * 4);
        float inv = (rnr > 0.f) ? (1.0f / rnr) : 0.f;  // x1 = a1/rnorm
        const float third = 1.0f / 3.0f;
        f32x4 o;
        o[0] = (x0[0] + (float)a1[0] * inv + acc[0] * rnr) * third;
        o[1] = (x0[1] + (float)a1[1] * inv + acc[1] * rnr) * third;
        o[2] = (x0[2] + (float)a1[2] * inv + acc[2] * rnr) * third;
        o[3] = (x0[3] + (float)a1[3] * inv + acc[3] * rnr) * third;
        __builtin_nontemporal_store(
            o, reinterpret_cast<f32x4*>(y + (size_t)row * DIM + lane * 4));
    }
}

// ---------------- host ----------------

static inline int grid_for(long long work, int block, int cap = 4096) {
    long long b = (work + block - 1) / block;
    if (b > cap) b = cap;
    if (b < 1) b = 1;
    return (int)b;
}

extern "C" void kernel_launch(void* const* d_in, const int* in_sizes, int n_in,
                              void* d_out, int out_size, void* d_ws, size_t ws_size,
                              hipStream_t stream) {
    const float* u_emb = (const float*)d_in[0];
    const float* i_emb = (const float*)d_in[1];
    const int* u_idx = (const int*)d_in[2];
    const int* i_idx = (const int*)d_in[3];

    const int n_u = in_sizes[0] / DIM;
    const int n_i = in_sizes[1] / DIM;
    const int n = n_u + n_i;
    const int E = in_sizes[2];
    const int twoE = 2 * E;
    const int NB = (n + 1023) / 1024;  // scan blocks (<= 512)

    // workspace layout
    char* w = (char*)d_ws;
    auto alloc = [&](size_t bytes) -> void* {
        void* p = (void*)w;
        w += (bytes + 255) & ~(size_t)255;
        return p;
    };
    f16*   xh0     = (f16*)alloc((size_t)n * DIM * sizeof(f16));  // rnorm-scaled x0, fp16
    f16*   xh1     = (f16*)alloc((size_t)n * DIM * sizeof(f16));  // rnorm-scaled x1, fp16
    float* rnorm   = (float*)alloc((size_t)n * sizeof(float));
    int*   degcur  = (int*)alloc((size_t)(2 * n) * sizeof(int));  // deg | cursor (one memset)
    int*   deg     = degcur;
    int*   cursor  = degcur + n;
    int*   row_ptr = (int*)alloc((size_t)(n + 1) * sizeof(int));
    int*   adj     = (int*)alloc((size_t)twoE * sizeof(int));
    int*   parts   = (int*)alloc((size_t)NB * sizeof(int));
    int*   offs    = (int*)alloc((size_t)NB * sizeof(int));
    (void)ws_size;

    hipMemsetAsync(degcur, 0, (size_t)(2 * n) * sizeof(int), stream);

    k_count<<<grid_for(twoE, 256, 2048), 256, 0, stream>>>(u_idx, i_idx, E, n_u, deg);
    k_scan1<<<NB, 256, 0, stream>>>(deg, n, parts, rnorm);
    k_scan2<<<1, 512, 0, stream>>>(parts, offs, NB);
    k_scan3<<<NB, 256, 0, stream>>>(deg, n, offs, row_ptr, twoE);
    k_fill<<<grid_for(twoE, 256, 2048), 256, 0, stream>>>(u_idx, i_idx, E, n_u, row_ptr,
                                                          cursor, adj);
    k_scale_h<<<grid_for((long long)n * 32, 256, 8192), 256, 0, stream>>>(u_emb, i_emb, rnorm,
                                                                          n_u, n, xh0);

    int sblocks = (int)(((long long)n * 32 + 255) / 256);
    // layer 1: xh1 = fp16( rnorm^2 * (A_unw @ xh0) ) = rnorm .* x1   (fp16)
    k_spmm<0><<<sblocks, 256, 0, stream>>>(row_ptr, adj, rnorm, xh0, nullptr, nullptr,
                                           n_u, n, nullptr, xh1);
    // layer 2 + fused combine: out = (x0 + xh1/rnorm + rnorm*(A_unw @ xh1))/3
    k_spmm<1><<<sblocks, 256, 0, stream>>>(row_ptr, adj, rnorm, xh1, u_emb, i_emb,
                                           n_u, n, (float*)d_out, nullptr);
}

// Round 4
// 605.162 us; speedup vs baseline: 1.1279x; 1.0124x over previous
//
#include <hip/hip_runtime.h>

#define DIM 128

using f16 = _Float16;
using f16x4 = __attribute__((ext_vector_type(4))) f16;
using f32x4 = __attribute__((ext_vector_type(4))) float;

// ---------------- CSR build ----------------
// k_count / k_fill are random scatters. Plain grid-stride scatter ping-pongs
// cache lines across the 8 XCDs (each 64B adj line receives ~15 stores from
// different XCDs -> exclusive-ownership migration -> partial-line HBM flushes;
// measured 195 MB WRITE for a 12 MB array, round-3 post-mortem).
// Fix: destination windowing by XCD. Block group x (blockIdx&7 == x, resident
// on XCD x under the %8 round-robin dispatch) scans the WHOLE edge list but
// scatters only into destination window [x*n/8,(x+1)*n/8). Its 1.5 MB adj
// window then lives exclusively in XCD x's L2 and evicts as full lines.
// The 8x re-read of the 12 MB index stream is L3-absorbed (sequential, NT).

__global__ void k_count(const int* __restrict__ u_idx, const int* __restrict__ i_idx,
                        int E, int n_u, int n, int* __restrict__ deg) {
    int grp = blockIdx.x & 7;
    int gb  = blockIdx.x >> 3;
    int ngb = gridDim.x >> 3;
    int lo = (int)((long long)n * grp / 8);
    int hi = (int)((long long)n * (grp + 1) / 8);
    int i = gb * blockDim.x + threadIdx.x;
    int stride = ngb * blockDim.x;
    for (; i < E; i += stride) {
        int u = __builtin_nontemporal_load(&u_idx[i]);
        int t = __builtin_nontemporal_load(&i_idx[i]) + n_u;
        if (u >= lo && u < hi) atomicAdd(&deg[u], 1);
        if (t >= lo && t < hi) atomicAdd(&deg[t], 1);
    }
}

// exclusive scan over deg (3 kernels, n up to 512*1024)
// scan1 also emits rnorm (free fusion: same pass over deg)
__global__ void k_scan1(const int* __restrict__ deg, int n, int* __restrict__ partials,
                        float* __restrict__ rnorm) {
    __shared__ int sh[256];
    int tid = threadIdx.x;
    int base = blockIdx.x * 1024 + tid * 4;
    int s = 0;
#pragma unroll
    for (int j = 0; j < 4; ++j) {
        int idx = base + j;
        if (idx < n) {
            int d = deg[idx];
            s += d;
            // reference deg = 2*d (bincount over [r,c]); rows with d==0 never feed edges
            rnorm[idx] = (d > 0) ? rsqrtf(2.0f * (float)d) : 0.0f;
        }
    }
    sh[tid] = s;
    __syncthreads();
    for (int off = 128; off > 0; off >>= 1) {
        if (tid < off) sh[tid] += sh[tid + off];
        __syncthreads();
    }
    if (tid == 0) partials[blockIdx.x] = sh[0];
}

__global__ void k_scan2(const int* __restrict__ partials, int* __restrict__ offsets, int NB) {
    __shared__ int sh[512];
    int tid = threadIdx.x;
    int v = (tid < NB) ? partials[tid] : 0;
    sh[tid] = v;
    __syncthreads();
    for (int off = 1; off < 512; off <<= 1) {
        int t = (tid >= off) ? sh[tid - off] : 0;
        __syncthreads();
        sh[tid] += t;
        __syncthreads();
    }
    if (tid < NB) offsets[tid] = sh[tid] - v;  // exclusive
}

__global__ void k_scan3(const int* __restrict__ deg, int n,
                        const int* __restrict__ offsets, int* __restrict__ row_ptr, int twoE) {
    __shared__ int sh[256];
    int tid = threadIdx.x;
    int base = blockIdx.x * 1024 + tid * 4;
    int v[4];
    int ts = 0;
#pragma unroll
    for (int j = 0; j < 4; ++j) {
        int idx = base + j;
        v[j] = (idx < n) ? deg[idx] : 0;
        ts += v[j];
    }
    sh[tid] = ts;
    __syncthreads();
    for (int off = 1; off < 256; off <<= 1) {
        int t = (tid >= off) ? sh[tid - off] : 0;
        __syncthreads();
        sh[tid] += t;
        __syncthreads();
    }
    int run = sh[tid] - ts + offsets[blockIdx.x];
#pragma unroll
    for (int j = 0; j < 4; ++j) {
        int idx = base + j;
        if (idx < n) row_ptr[idx] = run;
        run += v[j];
    }
    if (blockIdx.x == 0 && tid == 0) row_ptr[n] = twoE;
}

// adjacency fill, XCD-windowed (see comment above k_count).
// scattered stores NORMAL (L2 write-combining within the owning XCD);
// idx streams NT (keep the L2 for the adj/cursor/row_ptr window).
__global__ void k_fill(const int* __restrict__ u_idx, const int* __restrict__ i_idx,
                       int E, int n_u, int n, const int* __restrict__ row_ptr,
                       int* __restrict__ cursor, int* __restrict__ adj) {
    int grp = blockIdx.x & 7;
    int gb  = blockIdx.x >> 3;
    int ngb = gridDim.x >> 3;
    int lo = (int)((long long)n * grp / 8);
    int hi = (int)((long long)n * (grp + 1) / 8);
    int i = gb * blockDim.x + threadIdx.x;
    int stride = ngb * blockDim.x;
    for (; i < E; i += stride) {
        int u = __builtin_nontemporal_load(&u_idx[i]);
        int t = __builtin_nontemporal_load(&i_idx[i]) + n_u;
        if (u >= lo && u < hi) {
            int pos = atomicAdd(&cursor[u], 1);
            adj[row_ptr[u] + pos] = t;
        }
        if (t >= lo && t < hi) {
            int pos = atomicAdd(&cursor[t], 1);
            adj[row_ptr[t] + pos] = u;
        }
    }
}

// fp16 pre-scaled gather source: xh[v] = fp16(rnorm[v] * x0[v]).
// NT load of emb (streamed; re-read only much later in MODE-1),
// NORMAL store of xh (it is the gather table — must stay cache-resident).
__global__ void k_scale_h(const float* __restrict__ u_emb, const float* __restrict__ i_emb,
                          const float* __restrict__ rnorm, int n_u, int n,
                          f16* __restrict__ xh) {
    int g = blockIdx.x * blockDim.x + threadIdx.x;
    int stride = gridDim.x * blockDim.x;
    int total = n * 32;
    for (; g < total; g += stride) {
        int v = g >> 5;
        int lane = g & 31;
        const float* src = (v < n_u) ? (u_emb + (size_t)v * DIM)
                                     : (i_emb + (size_t)(v - n_u) * DIM);
        float r = rnorm[v];
        f32x4 x = __builtin_nontemporal_load(
            reinterpret_cast<const f32x4*>(src + lane * 4));
        f16x4 o;
        o[0] = (f16)(x[0] * r);
        o[1] = (f16)(x[1] * r);
        o[2] = (f16)(x[2] * r);
        o[3] = (f16)(x[3] * r);
        *reinterpret_cast<f16x4*>(xh + (size_t)v * DIM + lane * 4) = o;
    }
}

// ---------------- SpMM ----------------
// One 32-lane half-wave per row; 4 fp16 elements (8B) per lane (128 = 32*4).
// Gather source xh is ALWAYS pre-scaled by rnorm[c] (weights folded) -> no
// per-edge weight gather in either layer.
// MODE 0: writes yh[row] = fp16(rnorm[row]^2 * sum) = fp16(rnorm[row]*x1[row])
//         (the pre-scaled gather operand for layer 2) — NORMAL store (table).
// MODE 1: writes y[row] = (x0 + x1 + rnorm[row]*sum)/3, recovering
//         x1[row] = yh1[row]/rnorm[row] (deg-0 rows: x1 = 0, guarded).
//         x0 load + y store are NT (pure streams, keep L3 for the table).
// Tail is predicated with clamped indices so 4 gathers stay in flight
// (clamped duplicates hit the just-fetched L1 line — free).

template <int MODE>
__global__ __launch_bounds__(256) void k_spmm(const int* __restrict__ row_ptr,
                                              const int* __restrict__ adj,
                                              const float* __restrict__ rnorm,
                                              const f16* __restrict__ xh,
                                              const float* __restrict__ u_emb,
                                              const float* __restrict__ i_emb,
                                              int n_u, int n,
                                              float* __restrict__ y,
                                              f16* __restrict__ yh) {
    int g = blockIdx.x * blockDim.x + threadIdx.x;
    int row = g >> 5;
    int lane = g & 31;
    if (row >= n) return;
    int s = row_ptr[row];
    int e = row_ptr[row + 1];
    float rnr = rnorm[row];
    f32x4 acc = {0.f, 0.f, 0.f, 0.f};
    const f16* xb = xh + lane * 4;
    int e1 = e - 1;
    for (int k = s; k < e; k += 4) {
        int k1 = k + 1, k2 = k + 2, k3 = k + 3;
        int c0 = adj[k];
        int c1 = adj[(k1 <= e1) ? k1 : e1];
        int c2 = adj[(k2 <= e1) ? k2 : e1];
        int c3 = adj[(k3 <= e1) ? k3 : e1];
        float w1 = (k1 < e) ? 1.f : 0.f;
        float w2 = (k2 < e) ? 1.f : 0.f;
        float w3 = (k3 < e) ? 1.f : 0.f;
        f16x4 v0 = *reinterpret_cast<const f16x4*>(xb + (size_t)c0 * DIM);
        f16x4 v1 = *reinterpret_cast<const f16x4*>(xb + (size_t)c1 * DIM);
        f16x4 v2 = *reinterpret_cast<const f16x4*>(xb + (size_t)c2 * DIM);
        f16x4 v3 = *reinterpret_cast<const f16x4*>(xb + (size_t)c3 * DIM);
        acc[0] += (float)v0[0];
        acc[1] += (float)v0[1];
        acc[2] += (float)v0[2];
        acc[3] += (float)v0[3];
        acc[0] = fmaf((float)v1[0], w1, acc[0]);
        acc[1] = fmaf((float)v1[1], w1, acc[1]);
        acc[2] = fmaf((float)v1[2], w1, acc[2]);
        acc[3] = fmaf((float)v1[3], w1, acc[3]);
        acc[0] = fmaf((float)v2[0], w2, acc[0]);
        acc[1] = fmaf((float)v2[1], w2, acc[1]);
        acc[2] = fmaf((float)v2[2], w2, acc[2]);
        acc[3] = fmaf((float)v2[3], w2, acc[3]);
        acc[0] = fmaf((float)v3[0], w3, acc[0]);
        acc[1] = fmaf((float)v3[1], w3, acc[1]);
        acc[2] = fmaf((float)v3[2], w3, acc[2]);
        acc[3] = fmaf((float)v3[3], w3, acc[3]);
    }
    if (MODE == 0) {
        float sc = rnr * rnr;  // store rnorm[row] * x1[row]
        f16x4 h;
        h[0] = (f16)(acc[0] * sc);
        h[1] = (f16)(acc[1] * sc);
        h[2] = (f16)(acc[2] * sc);
        h[3] = (f16)(acc[3] * sc);
        *reinterpret_cast<f16x4*>(yh + (size_t)row * DIM + lane * 4) = h;
    } else {
        const float* x0b = (row < n_u) ? (u_emb + (size_t)row * DIM)
                                       : (i_emb + (size_t)(row - n_u) * DIM);
        f32x4 x0 = __builtin_nontemporal_load(
            reinterpret_cast<const f32x4*>(x0b + lane * 4));
        f16x4 a1 = *reinterpret_cast<const f16x4*>(xh + (size_t)row * DIM + lane * 4);
        float inv = (rnr > 0.f) ? (1.0f / rnr) : 0.f;  // x1 = a1/rnorm
        const float third = 1.0f / 3.0f;
        f32x4 o;
        o[0] = (x0[0] + (float)a1[0] * inv + acc[0] * rnr) * third;
        o[1] = (x0[1] + (float)a1[1] * inv + acc[1] * rnr) * third;
        o[2] = (x0[2] + (float)a1[2] * inv + acc[2] * rnr) * third;
        o[3] = (x0[3] + (float)a1[3] * inv + acc[3] * rnr) * third;
        __builtin_nontemporal_store(
            o, reinterpret_cast<f32x4*>(y + (size_t)row * DIM + lane * 4));
    }
}

// ---------------- host ----------------

static inline int grid_for(long long work, int block, int cap = 4096) {
    long long b = (work + block - 1) / block;
    if (b > cap) b = cap;
    if (b < 1) b = 1;
    return (int)b;
}

extern "C" void kernel_launch(void* const* d_in, const int* in_sizes, int n_in,
                              void* d_out, int out_size, void* d_ws, size_t ws_size,
                              hipStream_t stream) {
    const float* u_emb = (const float*)d_in[0];
    const float* i_emb = (const float*)d_in[1];
    const int* u_idx = (const int*)d_in[2];
    const int* i_idx = (const int*)d_in[3];

    const int n_u = in_sizes[0] / DIM;
    const int n_i = in_sizes[1] / DIM;
    const int n = n_u + n_i;
    const int E = in_sizes[2];
    const int twoE = 2 * E;
    const int NB = (n + 1023) / 1024;  // scan blocks (<= 512)

    // workspace layout
    char* w = (char*)d_ws;
    auto alloc = [&](size_t bytes) -> void* {
        void* p = (void*)w;
        w += (bytes + 255) & ~(size_t)255;
        return p;
    };
    f16*   xh0     = (f16*)alloc((size_t)n * DIM * sizeof(f16));  // rnorm-scaled x0, fp16
    f16*   xh1     = (f16*)alloc((size_t)n * DIM * sizeof(f16));  // rnorm-scaled x1, fp16
    float* rnorm   = (float*)alloc((size_t)n * sizeof(float));
    int*   degcur  = (int*)alloc((size_t)(2 * n) * sizeof(int));  // deg | cursor (one memset)
    int*   deg     = degcur;
    int*   cursor  = degcur + n;
    int*   row_ptr = (int*)alloc((size_t)(n + 1) * sizeof(int));
    int*   adj     = (int*)alloc((size_t)twoE * sizeof(int));
    int*   parts   = (int*)alloc((size_t)NB * sizeof(int));
    int*   offs    = (int*)alloc((size_t)NB * sizeof(int));
    (void)ws_size;

    hipMemsetAsync(degcur, 0, (size_t)(2 * n) * sizeof(int), stream);

    // XCD-windowed scatters: grid multiple of 8 (blockIdx&7 -> XCD group)
    k_count<<<2048, 256, 0, stream>>>(u_idx, i_idx, E, n_u, n, deg);
    k_scan1<<<NB, 256, 0, stream>>>(deg, n, parts, rnorm);
    k_scan2<<<1, 512, 0, stream>>>(parts, offs, NB);
    k_scan3<<<NB, 256, 0, stream>>>(deg, n, offs, row_ptr, twoE);
    k_fill<<<2048, 256, 0, stream>>>(u_idx, i_idx, E, n_u, n, row_ptr, cursor, adj);
    k_scale_h<<<grid_for((long long)n * 32, 256, 8192), 256, 0, stream>>>(u_emb, i_emb, rnorm,
                                                                          n_u, n, xh0);

    int sblocks = (int)(((long long)n * 32 + 255) / 256);
    // layer 1: xh1 = fp16( rnorm^2 * (A_unw @ xh0) ) = rnorm .* x1   (fp16)
    k_spmm<0><<<sblocks, 256, 0, stream>>>(row_ptr, adj, rnorm, xh0, nullptr, nullptr,
                                           n_u, n, nullptr, xh1);
    // layer 2 + fused combine: out = (x0 + xh1/rnorm + rnorm*(A_unw @ xh1))/3
    k_spmm<1><<<sblocks, 256, 0, stream>>>(row_ptr, adj, rnorm, xh1, u_emb, i_emb,
                                           n_u, n, (float*)d_out, nullptr);
}